// Round 7
// baseline (553.016 us; speedup 1.0000x reference)
//
#include <hip/hip_runtime.h>

#define SEQ 1024
#define NT  16    // 16 iterations; per iter each wave handles 16 rows

typedef unsigned short u16;
typedef unsigned int   u32;
typedef __bf16 bf16x8 __attribute__((ext_vector_type(8)));
typedef float  f32x4  __attribute__((ext_vector_type(4)));

__device__ __forceinline__ float fast_tanh(float x) {
    float e = __expf(x + x);
    return 1.0f - 2.0f * __builtin_amdgcn_rcpf(e + 1.0f);
}

// wave-local direct-to-register tile load in MFMA A-frag layout:
// lane (lo,hi) gets row = base+lo, k = ks*32 + hi*8 .. +7  (8 dwordx4)
#define LOADT(tt)                                                            \
    do {                                                                     \
        int rowb = ((tt)*64 + w*16 + lo)*32 + hi*2;                          \
        _Pragma("unroll")                                                    \
        for (int ks = 0; ks < 4; ++ks) {                                     \
            rr[2*ks]   = hs4[rowb + ks*8];                                   \
            rr[2*ks+1] = hs4[rowb + ks*8 + 1];                               \
        }                                                                    \
    } while (0)

#define CVT8(dst, vlo, vhi)                                                  \
    { dst[0]=(__bf16)(vlo)[0]; dst[1]=(__bf16)(vlo)[1];                      \
      dst[2]=(__bf16)(vlo)[2]; dst[3]=(__bf16)(vlo)[3];                      \
      dst[4]=(__bf16)(vhi)[0]; dst[5]=(__bf16)(vhi)[1];                      \
      dst[6]=(__bf16)(vhi)[2]; dst[7]=(__bf16)(vhi)[3]; }

#define CVTALL                                                               \
    CVT8(aa0, rr[0], rr[1]); CVT8(aa1, rr[2], rr[3]);                        \
    CVT8(aa2, rr[4], rr[5]); CVT8(aa3, rr[6], rr[7]);

// B-frag from swizzled LDS Ut: col = n*16+lo, kblk = ks*4+hi, block ^= lo
#define BF(n, ks) (*(const bf16x8*)&Ut[(n)*2048 + lo*128 + ((((ks)*4+hi) ^ lo) << 3)])

// ht_proj folded into MFMA C-init: acc rows all get htpR[n] (col n*16+lo)
#define NSTEP(n)                                                             \
    do {                                                                     \
        float hC = htpR[n];                                                  \
        f32x4 acc = {hC, hC, hC, hC};                                        \
        acc = __builtin_amdgcn_mfma_f32_16x16x32_bf16(aa0, BF(n,0), acc, 0, 0, 0); \
        acc = __builtin_amdgcn_mfma_f32_16x16x32_bf16(aa1, BF(n,1), acc, 0, 0, 0); \
        acc = __builtin_amdgcn_mfma_f32_16x16x32_bf16(aa2, BF(n,2), acc, 0, 0, 0); \
        acc = __builtin_amdgcn_mfma_f32_16x16x32_bf16(aa3, BF(n,3), acc, 0, 0, 0); \
        float vC = VsR[n];                                                   \
        part0 += fast_tanh(acc[0]) * vC;                                     \
        part1 += fast_tanh(acc[1]) * vC;                                     \
        part2 += fast_tanh(acc[2]) * vC;                                     \
        part3 += fast_tanh(acc[3]) * vC;                                     \
    } while (0)

// context accumulate from bf16 A-frags (rr already dead)
#define CTX(ks, AA)                                                          \
    { f32x4 t0 = {(float)AA[0], (float)AA[1], (float)AA[2], (float)AA[3]};   \
      f32x4 t1 = {(float)AA[4], (float)AA[5], (float)AA[6], (float)AA[7]};   \
      c_part[2*(ks)]   += wr * t0;                                           \
      c_part[2*(ks)+1] += wr * t1; }

// scores -> softmax weights -> context, all register/shuffle (no LDS)
#define REST                                                                 \
    do {                                                                     \
        float part0 = 0.f, part1 = 0.f, part2 = 0.f, part3 = 0.f;            \
        __builtin_amdgcn_s_setprio(1);                                       \
        NSTEP(0); NSTEP(1); NSTEP(2); NSTEP(3);                              \
        NSTEP(4); NSTEP(5); NSTEP(6); NSTEP(7);                              \
        __builtin_amdgcn_s_setprio(0);                                       \
        _Pragma("unroll")                                                    \
        for (int msk = 1; msk < 16; msk <<= 1) {                             \
            part0 += __shfl_xor(part0, msk);                                 \
            part1 += __shfl_xor(part1, msk);                                 \
            part2 += __shfl_xor(part2, msk);                                 \
            part3 += __shfl_xor(part3, msk);                                 \
        }                                                                    \
        float e0 = __expf(part0), e1 = __expf(part1);                        \
        float e2 = __expf(part2), e3 = __expf(part3);                        \
        lsum += e0 + e1 + e2 + e3;                                           \
        /* lane(lo,hi) needs weight of row lo: pick e_{lo&3}, pull from      \
           lane (lo>>2)*16 + (lo&3) -- 3 cndmask + 1 bpermute, no LDS */     \
        float sel = (lo & 2) ? ((lo & 1) ? e3 : e2)                          \
                             : ((lo & 1) ? e1 : e0);                         \
        float wr  = __shfl(sel, (lo >> 2) * 16 + (lo & 3), 64);              \
        CTX(0, aa0); CTX(1, aa1); CTX(2, aa2); CTX(3, aa3);                  \
    } while (0)

__global__ __launch_bounds__(256) __attribute__((amdgpu_waves_per_eu(3)))
void attn_fused(const float* __restrict__ h_t, const float* __restrict__ h_s,
                const float* __restrict__ W_a, const float* __restrict__ U_a,
                const float* __restrict__ V_a, const float* __restrict__ W_c,
                const float* __restrict__ b_c, const float* __restrict__ gamma,
                const float* __restrict__ beta, float* __restrict__ out)
{
    // Ut: bf16 U^T [col h][k d], 16B-block-swizzled: blk' = kblk ^ (col&15)
    __shared__ u16 Ut[128*128];     // 32 KB
    __shared__ float htp[128];      // ht_proj, later context
    __shared__ float htrow[128];
    __shared__ float cw[512];       // per-wave context partials
    __shared__ float lw[4], lnp[4], lnq[4];

    const int tid = threadIdx.x;
    const int b   = blockIdx.x;
    const int w   = tid >> 6, l = tid & 63;
    const int lo  = l & 15,  hi = l >> 4;

    const f32x4* hs4 = (const f32x4*)(h_s + (size_t)b * (SEQ*128));

    // issue tile-0 loads first: in flight under the whole prologue
    f32x4 rr[8];
    LOADT(0);

    if (tid < 128) htrow[tid] = h_t[b*128 + tid];

    // ---- U_a -> bf16 transposed + swizzled in LDS ----
    const float4* U4 = (const float4*)U_a;
    #pragma unroll
    for (int i = 0; i < 16; ++i) {
        int f4i = i*256 + tid;
        float4 v = U4[f4i];
        int k  = f4i >> 5;          // d index
        int cb = (f4i & 31) * 4;    // h base
        float vv[4] = {v.x, v.y, v.z, v.w};
        #pragma unroll
        for (int j = 0; j < 4; ++j) {
            int c = cb + j;
            Ut[c*128 + (((k>>3) ^ (c&15)) << 3) + (k&7)] = __builtin_bit_cast(u16, (__bf16)vv[j]);
        }
    }
    __syncthreads();   // htrow + Ut ready

    // ht_proj = h_t[b] @ W_a
    if (tid < 128) {
        float acc = 0.f;
        #pragma unroll 4
        for (int d = 0; d < 128; ++d) acc += htrow[d] * W_a[d*128 + tid];
        htp[tid] = acc;
    }
    __syncthreads();   // htp visible

    float htpR[8], VsR[8];
    #pragma unroll
    for (int n = 0; n < 8; ++n) { htpR[n] = htp[n*16 + lo]; VsR[n] = V_a[n*16 + lo]; }

    float lsum = 0.f;
    f32x4 c_part[8];
    #pragma unroll
    for (int i = 0; i < 8; ++i) c_part[i] = (f32x4){0.f, 0.f, 0.f, 0.f};

    // single-buffer pipeline: rr consumed by CVT at iteration top, then
    // immediately reloaded for t+1 -> 8 loads in flight across REST.
    for (int t = 0; t < NT-1; ++t) {
        bf16x8 aa0, aa1, aa2, aa3;
        CVTALL;            // compiler auto-waits rr's loads (counted vmcnt)
        LOADT(t+1);        // reuse rr registers right away
        REST;
    }
    {
        bf16x8 aa0, aa1, aa2, aa3;
        CVTALL;
        REST;
    }

    // ---- reduce context over the 16 lo-lanes (once) ----
    #pragma unroll
    for (int i = 0; i < 8; ++i) {
        #pragma unroll
        for (int msk = 1; msk < 16; msk <<= 1) {
            c_part[i][0] += __shfl_xor(c_part[i][0], msk);
            c_part[i][1] += __shfl_xor(c_part[i][1], msk);
            c_part[i][2] += __shfl_xor(c_part[i][2], msk);
            c_part[i][3] += __shfl_xor(c_part[i][3], msk);
        }
    }
    float lt = lsum;               // lo-uniform; sum the 4 hi-groups
    lt += __shfl_xor(lt, 16);
    lt += __shfl_xor(lt, 32);
    if (l == 0) lw[w] = lt;
    if (lo == 0) {
        #pragma unroll
        for (int i = 0; i < 8; ++i)
            *(f32x4*)&cw[w*128 + (i>>1)*32 + hi*8 + (i&1)*4] = c_part[i];
    }
    __syncthreads();

    if (tid < 128) {
        float L = lw[0] + lw[1] + lw[2] + lw[3];
        float C = cw[tid] + cw[128 + tid] + cw[256 + tid] + cw[384 + tid];
        htp[tid] = C / L;   // context
    }
    __syncthreads();

    float av = 0.f;
    if (tid < 128) {
        float acc = b_c[tid];
        #pragma unroll 4
        for (int k = 0; k < 128; ++k) acc += htp[k]   * W_c[k*128 + tid];
        #pragma unroll 4
        for (int k = 0; k < 128; ++k) acc += htrow[k] * W_c[(128 + k)*128 + tid];
        av = fast_tanh(acc);
    }
    // LayerNorm over the 128 attn_vec values (threads 0..127 = waves 0,1)
    float s1 = (tid < 128) ? av : 0.f;
    #pragma unroll
    for (int msk = 1; msk < 64; msk <<= 1) s1 += __shfl_xor(s1, msk);
    if (l == 0) lnp[w] = s1;
    __syncthreads();
    float mu  = (lnp[0] + lnp[1]) * (1.f/128.f);
    float dev = av - mu;
    float s2 = (tid < 128) ? dev*dev : 0.f;
    #pragma unroll
    for (int msk = 1; msk < 64; msk <<= 1) s2 += __shfl_xor(s2, msk);
    if (l == 0) lnq[w] = s2;
    __syncthreads();
    float var = (lnq[0] + lnq[1]) * (1.f/128.f);
    if (tid < 128) {
        out[b*128 + tid] = dev * rsqrtf(var + 1e-3f) * gamma[tid] + beta[tid];
    }
}

extern "C" void kernel_launch(void* const* d_in, const int* in_sizes, int n_in,
                              void* d_out, int out_size, void* d_ws, size_t ws_size,
                              hipStream_t stream) {
    const float* h_t  = (const float*)d_in[0];
    const float* h_s  = (const float*)d_in[1];
    const float* W_a  = (const float*)d_in[2];
    const float* U_a  = (const float*)d_in[3];
    const float* V_a  = (const float*)d_in[4];
    const float* W_c  = (const float*)d_in[5];
    const float* b_c  = (const float*)d_in[6];
    const float* gam  = (const float*)d_in[7];
    const float* bet  = (const float*)d_in[8];
    float* out = (float*)d_out;
    hipLaunchKernelGGL(attn_fused, dim3(1024), dim3(256), 0, stream,
                       h_t, h_s, W_a, U_a, V_a, W_c, b_c, gam, bet, out);
}

// Round 8
// 550.876 us; speedup vs baseline: 1.0039x; 1.0039x over previous
//
#include <hip/hip_runtime.h>

#define SEQ 1024
#define NT  16    // 16 iterations; per iter each wave handles 16 rows

typedef unsigned short u16;
typedef unsigned int   u32;
typedef __bf16 bf16x8 __attribute__((ext_vector_type(8)));
typedef float  f32x4  __attribute__((ext_vector_type(4)));

__device__ __forceinline__ float fast_tanh(float x) {
    float e = __expf(x + x);
    return 1.0f - 2.0f * __builtin_amdgcn_rcpf(e + 1.0f);
}

// wave-local direct-to-register tile load in MFMA A-frag layout:
// lane (lo,hi) gets row = base+lo, k = ks*32 + hi*8 .. +7  (8 dwordx4)
#define LOADT(tt)                                                            \
    do {                                                                     \
        int rowb = ((tt)*64 + w*16 + lo)*32 + hi*2;                          \
        _Pragma("unroll")                                                    \
        for (int ks = 0; ks < 4; ++ks) {                                     \
            rr[2*ks]   = hs4[rowb + ks*8];                                   \
            rr[2*ks+1] = hs4[rowb + ks*8 + 1];                               \
        }                                                                    \
    } while (0)

#define CVT8(dst, vlo, vhi)                                                  \
    { dst[0]=(__bf16)(vlo)[0]; dst[1]=(__bf16)(vlo)[1];                      \
      dst[2]=(__bf16)(vlo)[2]; dst[3]=(__bf16)(vlo)[3];                      \
      dst[4]=(__bf16)(vhi)[0]; dst[5]=(__bf16)(vhi)[1];                      \
      dst[6]=(__bf16)(vhi)[2]; dst[7]=(__bf16)(vhi)[3]; }

#define CVTALL                                                               \
    CVT8(aa0, rr[0], rr[1]); CVT8(aa1, rr[2], rr[3]);                        \
    CVT8(aa2, rr[4], rr[5]); CVT8(aa3, rr[6], rr[7]);

// B-frag from swizzled LDS Ut: col = n*16+lo, kblk = ks*4+hi, block ^= lo
#define BF(n, ks) (*(const bf16x8*)&Ut[(n)*2048 + lo*128 + ((((ks)*4+hi) ^ lo) << 3)])

// ht_proj folded into MFMA C-init: acc rows all get htpR[n] (col n*16+lo)
#define NSTEP(n)                                                             \
    do {                                                                     \
        float hC = htpR[n];                                                  \
        f32x4 acc = {hC, hC, hC, hC};                                        \
        acc = __builtin_amdgcn_mfma_f32_16x16x32_bf16(aa0, BF(n,0), acc, 0, 0, 0); \
        acc = __builtin_amdgcn_mfma_f32_16x16x32_bf16(aa1, BF(n,1), acc, 0, 0, 0); \
        acc = __builtin_amdgcn_mfma_f32_16x16x32_bf16(aa2, BF(n,2), acc, 0, 0, 0); \
        acc = __builtin_amdgcn_mfma_f32_16x16x32_bf16(aa3, BF(n,3), acc, 0, 0, 0); \
        float vC = VsR[n];                                                   \
        part0 += fast_tanh(acc[0]) * vC;                                     \
        part1 += fast_tanh(acc[1]) * vC;                                     \
        part2 += fast_tanh(acc[2]) * vC;                                     \
        part3 += fast_tanh(acc[3]) * vC;                                     \
    } while (0)

// context accumulate from bf16 A-frags (rr already dead)
#define CTX(ks, AA)                                                          \
    { f32x4 t0 = {(float)AA[0], (float)AA[1], (float)AA[2], (float)AA[3]};   \
      f32x4 t1 = {(float)AA[4], (float)AA[5], (float)AA[6], (float)AA[7]};   \
      c_part[2*(ks)]   += wr * t0;                                           \
      c_part[2*(ks)+1] += wr * t1; }

// scores -> softmax weights -> context, all register/shuffle (no LDS)
#define REST                                                                 \
    do {                                                                     \
        float part0 = 0.f, part1 = 0.f, part2 = 0.f, part3 = 0.f;            \
        __builtin_amdgcn_s_setprio(1);                                       \
        NSTEP(0); NSTEP(1); NSTEP(2); NSTEP(3);                              \
        NSTEP(4); NSTEP(5); NSTEP(6); NSTEP(7);                              \
        __builtin_amdgcn_s_setprio(0);                                       \
        _Pragma("unroll")                                                    \
        for (int msk = 1; msk < 16; msk <<= 1) {                             \
            part0 += __shfl_xor(part0, msk);                                 \
            part1 += __shfl_xor(part1, msk);                                 \
            part2 += __shfl_xor(part2, msk);                                 \
            part3 += __shfl_xor(part3, msk);                                 \
        }                                                                    \
        float e0 = __expf(part0), e1 = __expf(part1);                        \
        float e2 = __expf(part2), e3 = __expf(part3);                        \
        lsum += e0 + e1 + e2 + e3;                                           \
        /* lane(lo,hi) needs weight of row lo: pick e_{lo&3}, pull from      \
           lane (lo>>2)*16 + (lo&3) -- 3 cndmask + 1 bpermute, no LDS */     \
        float sel = (lo & 2) ? ((lo & 1) ? e3 : e2)                          \
                             : ((lo & 1) ? e1 : e0);                         \
        float wr  = __shfl(sel, (lo >> 2) * 16 + (lo & 3), 64);              \
        CTX(0, aa0); CTX(1, aa1); CTX(2, aa2); CTX(3, aa3);                  \
    } while (0)

__global__ __launch_bounds__(256, 3)
void attn_fused(const float* __restrict__ h_t, const float* __restrict__ h_s,
                const float* __restrict__ W_a, const float* __restrict__ U_a,
                const float* __restrict__ V_a, const float* __restrict__ W_c,
                const float* __restrict__ b_c, const float* __restrict__ gamma,
                const float* __restrict__ beta, float* __restrict__ out)
{
    // Ut: bf16 U^T [col h][k d], 16B-block-swizzled: blk' = kblk ^ (col&15)
    __shared__ u16 Ut[128*128];     // 32 KB
    __shared__ float htp[128];      // ht_proj, later context
    __shared__ float htrow[128];
    __shared__ float cw[512];       // per-wave context partials
    __shared__ float lw[4], lnp[4], lnq[4];

    const int tid = threadIdx.x;
    const int b   = blockIdx.x;
    const int w   = tid >> 6, l = tid & 63;
    const int lo  = l & 15,  hi = l >> 4;

    const f32x4* hs4 = (const f32x4*)(h_s + (size_t)b * (SEQ*128));

    // issue tile-0 loads first: in flight under the whole prologue
    f32x4 rr[8];
    LOADT(0);

    if (tid < 128) htrow[tid] = h_t[b*128 + tid];

    // ---- U_a -> bf16 transposed + swizzled in LDS ----
    const float4* U4 = (const float4*)U_a;
    #pragma unroll
    for (int i = 0; i < 16; ++i) {
        int f4i = i*256 + tid;
        float4 v = U4[f4i];
        int k  = f4i >> 5;          // d index
        int cb = (f4i & 31) * 4;    // h base
        float vv[4] = {v.x, v.y, v.z, v.w};
        #pragma unroll
        for (int j = 0; j < 4; ++j) {
            int c = cb + j;
            Ut[c*128 + (((k>>3) ^ (c&15)) << 3) + (k&7)] = __builtin_bit_cast(u16, (__bf16)vv[j]);
        }
    }
    __syncthreads();   // htrow + Ut ready

    // ht_proj = h_t[b] @ W_a
    if (tid < 128) {
        float acc = 0.f;
        #pragma unroll 4
        for (int d = 0; d < 128; ++d) acc += htrow[d] * W_a[d*128 + tid];
        htp[tid] = acc;
    }
    __syncthreads();   // htp visible

    float htpR[8], VsR[8];
    #pragma unroll
    for (int n = 0; n < 8; ++n) { htpR[n] = htp[n*16 + lo]; VsR[n] = V_a[n*16 + lo]; }

    float lsum = 0.f;
    f32x4 c_part[8];
    #pragma unroll
    for (int i = 0; i < 8; ++i) c_part[i] = (f32x4){0.f, 0.f, 0.f, 0.f};

    // single-buffer pipeline: rr consumed by CVT at iteration top, then
    // immediately reloaded for t+1 -> 8 loads in flight across REST.
    for (int t = 0; t < NT-1; ++t) {
        bf16x8 aa0, aa1, aa2, aa3;
        CVTALL;            // compiler auto-waits rr's loads (counted vmcnt)
        LOADT(t+1);        // reuse rr registers right away
        REST;
    }
    {
        bf16x8 aa0, aa1, aa2, aa3;
        CVTALL;
        REST;
    }

    // ---- reduce context over the 16 lo-lanes (once) ----
    #pragma unroll
    for (int i = 0; i < 8; ++i) {
        #pragma unroll
        for (int msk = 1; msk < 16; msk <<= 1) {
            c_part[i][0] += __shfl_xor(c_part[i][0], msk);
            c_part[i][1] += __shfl_xor(c_part[i][1], msk);
            c_part[i][2] += __shfl_xor(c_part[i][2], msk);
            c_part[i][3] += __shfl_xor(c_part[i][3], msk);
        }
    }
    float lt = lsum;               // lo-uniform; sum the 4 hi-groups
    lt += __shfl_xor(lt, 16);
    lt += __shfl_xor(lt, 32);
    if (l == 0) lw[w] = lt;
    if (lo == 0) {
        #pragma unroll
        for (int i = 0; i < 8; ++i)
            *(f32x4*)&cw[w*128 + (i>>1)*32 + hi*8 + (i&1)*4] = c_part[i];
    }
    __syncthreads();

    if (tid < 128) {
        float L = lw[0] + lw[1] + lw[2] + lw[3];
        float C = cw[tid] + cw[128 + tid] + cw[256 + tid] + cw[384 + tid];
        htp[tid] = C / L;   // context
    }
    __syncthreads();

    float av = 0.f;
    if (tid < 128) {
        float acc = b_c[tid];
        #pragma unroll 4
        for (int k = 0; k < 128; ++k) acc += htp[k]   * W_c[k*128 + tid];
        #pragma unroll 4
        for (int k = 0; k < 128; ++k) acc += htrow[k] * W_c[(128 + k)*128 + tid];
        av = fast_tanh(acc);
    }
    // LayerNorm over the 128 attn_vec values (threads 0..127 = waves 0,1)
    float s1 = (tid < 128) ? av : 0.f;
    #pragma unroll
    for (int msk = 1; msk < 64; msk <<= 1) s1 += __shfl_xor(s1, msk);
    if (l == 0) lnp[w] = s1;
    __syncthreads();
    float mu  = (lnp[0] + lnp[1]) * (1.f/128.f);
    float dev = av - mu;
    float s2 = (tid < 128) ? dev*dev : 0.f;
    #pragma unroll
    for (int msk = 1; msk < 64; msk <<= 1) s2 += __shfl_xor(s2, msk);
    if (l == 0) lnq[w] = s2;
    __syncthreads();
    float var = (lnq[0] + lnq[1]) * (1.f/128.f);
    if (tid < 128) {
        out[b*128 + tid] = dev * rsqrtf(var + 1e-3f) * gamma[tid] + beta[tid];
    }
}

extern "C" void kernel_launch(void* const* d_in, const int* in_sizes, int n_in,
                              void* d_out, int out_size, void* d_ws, size_t ws_size,
                              hipStream_t stream) {
    const float* h_t  = (const float*)d_in[0];
    const float* h_s  = (const float*)d_in[1];
    const float* W_a  = (const float*)d_in[2];
    const float* U_a  = (const float*)d_in[3];
    const float* V_a  = (const float*)d_in[4];
    const float* W_c  = (const float*)d_in[5];
    const float* b_c  = (const float*)d_in[6];
    const float* gam  = (const float*)d_in[7];
    const float* bet  = (const float*)d_in[8];
    float* out = (float*)d_out;
    hipLaunchKernelGGL(attn_fused, dim3(1024), dim3(256), 0, stream,
                       h_t, h_s, W_a, U_a, V_a, W_c, b_c, gam, bet, out);
}